// Round 1
// baseline (433.121 us; speedup 1.0000x reference)
//
#include <hip/hip_runtime.h>

// QuantizedKVCache: reference dequantizes the updated cache then overwrites
// the fresh-token window with exact fp values, so the output is
//   out[s,h,:] = (cache[s,h,:] - zp[s,h]) * scale[s,h]   (s outside window)
//   out[s,h,:] = val[s-pos,h,:]                          (s in [pos,pos+S_NEW))
// computed from the ORIGINAL inputs. Pure memory-bound stream:
// ~272 MiB read + 268 MiB write => roofline ~87 us at 6.3 TB/s copy rate.
//
// R3: persistent grid-stride form. rocprof showed our kernel BELOW the
// 164-us fillBuffer dispatches (so kernel < 163 us; dur_us 429 = ~2 fills
// + ~101 us kernel => kernel at ~5.4 TB/s, 86% of copy ceiling).
// Change: 2048 blocks x 256 thr (= 8 blocks/CU, 32 waves/CU resident,
// zero re-dispatch), each block walks 8 seq positions; per-block prologue
// (pos load, stream select) amortized 8x. Arithmetic kept as sub-then-mul
// to bit-match the JAX reference (absmax currently 0.0 - keep it).

// Fixed shapes: B=1, S_MAX=8192, H=32, D=128.
// fv4 units per seq position = H*D/4 = 1024; per token (s,h) = 32.

typedef int   iv4 __attribute__((ext_vector_type(4)));
typedef float fv4 __attribute__((ext_vector_type(4)));

__global__ __launch_bounds__(256, 8) void kv_dequant_fused(
    const fv4* __restrict__ k_val, const fv4* __restrict__ v_val,
    const iv4* __restrict__ k_cache, const iv4* __restrict__ v_cache,
    const float* __restrict__ k_scales, const float* __restrict__ v_scales,
    const int* __restrict__ k_zps, const int* __restrict__ v_zps,
    const int* __restrict__ pos_ptr,
    fv4* __restrict__ k_out, fv4* __restrict__ v_out,
    int nblk,    // seq positions per tensor = S_MAX = 8192
    int s_new)   // fresh seq positions = 128
{
    const int pos   = *pos_ptr;
    const int t     = threadIdx.x;
    const int nvirt = nblk << 1;         // k positions then v positions

    for (int p = blockIdx.x; p < nvirt; p += gridDim.x) {
        int b = p;
        const fv4*   val;
        const iv4*   cache;
        const float* scales;
        const int*   zps;
        fv4*         out;
        if (b < nblk) {
            val = k_val; cache = k_cache; scales = k_scales; zps = k_zps; out = k_out;
        } else {
            b -= nblk;
            val = v_val; cache = v_cache; scales = v_scales; zps = v_zps; out = v_out;
        }

        const int base4 = b << 10;       // fv4 index of this seq position
        const int rel   = b - pos;

        if (rel >= 0 && rel < s_new) {
            // fresh tokens: exact fp passthrough (block-uniform branch)
            const int vbase = rel << 10;
            #pragma unroll
            for (int j = 0; j < 4; ++j) {
                fv4 v = __builtin_nontemporal_load(&val[vbase + (j << 8) + t]);
                __builtin_nontemporal_store(v, &out[base4 + (j << 8) + t]);
            }
        } else {
            iv4   c[4];
            float sc[4];
            float zp[4];
            #pragma unroll
            for (int j = 0; j < 4; ++j) {
                const int idx   = base4 + (j << 8) + t;
                const int token = idx >> 5;       // s*H + h
                c[j]  = __builtin_nontemporal_load(&cache[idx]);
                sc[j] = scales[token];
                zp[j] = (float)zps[token];
            }
            #pragma unroll
            for (int j = 0; j < 4; ++j) {
                fv4 o;
                o.x = ((float)c[j].x - zp[j]) * sc[j];
                o.y = ((float)c[j].y - zp[j]) * sc[j];
                o.z = ((float)c[j].z - zp[j]) * sc[j];
                o.w = ((float)c[j].w - zp[j]) * sc[j];
                __builtin_nontemporal_store(o, &out[base4 + (j << 8) + t]);
            }
        }
    }
}

extern "C" void kernel_launch(void* const* d_in, const int* in_sizes, int n_in,
                              void* d_out, int out_size, void* d_ws, size_t ws_size,
                              hipStream_t stream) {
    const fv4*   k_val   = (const fv4*)d_in[0];
    const fv4*   v_val   = (const fv4*)d_in[1];
    const iv4*   k_cache = (const iv4*)d_in[2];
    const iv4*   v_cache = (const iv4*)d_in[3];
    const float* k_scale = (const float*)d_in[4];
    const float* v_scale = (const float*)d_in[5];
    const int*   k_zp    = (const int*)d_in[6];
    const int*   v_zp    = (const int*)d_in[7];
    const int*   pos     = (const int*)d_in[8];

    fv4* k_out = (fv4*)d_out;
    fv4* v_out = (fv4*)((float*)d_out + (out_size / 2));

    const int n4    = in_sizes[2] / 4;   // 8,388,608 fv4 per tensor
    const int nval4 = in_sizes[0] / 4;   //   131,072 fresh fv4
    const int nblk  = n4 >> 10;          // 8192 seq positions per tensor
    const int s_new = nval4 >> 10;       // 128 fresh seq positions

    const int nvirt = 2 * nblk;          // 16384 virtual blocks
    const int grid  = nvirt < 2048 ? nvirt : 2048;   // 8 blocks/CU, persistent

    kv_dequant_fused<<<grid, 256, 0, stream>>>(
        k_val, v_val, k_cache, v_cache, k_scale, v_scale, k_zp, v_zp, pos,
        k_out, v_out, nblk, s_new);
}